// Round 11
// baseline (2086.009 us; speedup 1.0000x reference)
//
#include <hip/hip_runtime.h>
#include <hip/hip_bf16.h>
#include <stdint.h>

// QM9 encoder: lin0 -> (NNConv + GRU) x3 -> Set2Set x3 -> lin1
// N=50000, E=100000, D=64, B=2500.
// k_msgf v3: wave = all 64 edges x 16-wide o-slice; W2 streamed from
// global/L2 (1MB, resident) -- no LDS staging, no in-loop barriers, no
// bank conflicts; registers ~120 (no spill). Fused contraction + scatter.

#define N_NODES 50000
#define N_EDGES 100000
#define NGRAPH  2500
#define FIN     11
#define EATT    5

typedef __attribute__((ext_vector_type(8))) short short8;
typedef __attribute__((ext_vector_type(4))) float f32x4;

__device__ __forceinline__ short8 zero8(){ short8 z = {0,0,0,0,0,0,0,0}; return z; }

__device__ __forceinline__ unsigned short f2bf(float x){
  unsigned u = __float_as_uint(x);
  u += 0x7FFFu + ((u >> 16) & 1u);   // RNE
  return (unsigned short)(u >> 16);
}
__device__ __forceinline__ float sigm(float x){ return 1.0f/(1.0f+__expf(-x)); }

// ================= front: weight-cvt + lin0 + mlp1 + deg =================
#define FB_CVT   2160          // 552960 / 256
#define FB_LIN0  12500         // N*64 / 256
#define FB_MLP1  50000         // E*128 / 256
#define FB_DEG   391           // ceil(E/256)
__global__ void k_front(const float* __restrict__ x, const float* __restrict__ l0w,
        const float* __restrict__ l0b, float* __restrict__ out, unsigned short* __restrict__ outb,
        const float* __restrict__ ea, const float* __restrict__ m1w, const float* __restrict__ m1b,
        unsigned short* __restrict__ hidb, const int* __restrict__ dst, float* __restrict__ deg,
        const float* __restrict__ mlp2w, const float* __restrict__ rootw,
        const float* __restrict__ wih, const float* __restrict__ whh,
        unsigned short* __restrict__ w2b, unsigned short* __restrict__ rootb,
        unsigned short* __restrict__ wihb, unsigned short* __restrict__ whhb){
  int bb = blockIdx.x;
  if (bb < FB_CVT){
    int i = bb*256 + threadIdx.x;
    if (i < 524288) w2b[i] = f2bf(mlp2w[i]);
    else if (i < 528384) rootb[i-524288] = f2bf(rootw[i-524288]);
    else if (i < 540672) wihb[i-528384] = f2bf(wih[i-528384]);
    else                 whhb[i-540672] = f2bf(whh[i-540672]);
  } else if (bb < FB_CVT + FB_LIN0){
    int t = (bb-FB_CVT)*256 + threadIdx.x;
    int n = t >> 6, o = t & 63;
    float s = l0b[o];
    #pragma unroll
    for (int f = 0; f < FIN; ++f) s += x[n*FIN+f]*l0w[o*FIN+f];
    s = fmaxf(s, 0.f);
    out[(size_t)n*64+o] = s; outb[(size_t)n*64+o] = f2bf(s);
  } else if (bb < FB_CVT + FB_LIN0 + FB_MLP1){
    int t = (bb-FB_CVT-FB_LIN0)*256 + threadIdx.x;
    int e = t >> 7, j = t & 127;
    float s = m1b[j];
    #pragma unroll
    for (int a = 0; a < EATT; ++a) s += ea[e*EATT+a]*m1w[j*EATT+a];
    hidb[(size_t)e*128+j] = f2bf(fmaxf(s,0.f));
  } else {
    int e = (bb-FB_CVT-FB_LIN0-FB_MLP1)*256 + threadIdx.x;
    if (e < N_EDGES) atomicAdd(&deg[dst[e]], 1.0f);
  }
}

// ====== fused NNConv message: agg[dst_e] += out[src_e] @ (hid_e@W2^T+b2) ======
// block = 64 edges, 4 waves. Wave covers ALL 64 edges x o-slice
// [wave*16, wave*16+16). Loop i=0..63: bfr = W2 rows i*64+wave*16+lm from
// GLOBAL (L2-resident, 1MB/block total); 16 MFMA (C^T: col=edge tile+lm,
// row=o=wave*16+4g+r, verified r2/r6); msgacc += (acc+b2)*os[edge][i].
// No in-loop barriers, no W2 LDS.
__global__ __launch_bounds__(256) void k_msgf(const unsigned short* __restrict__ hidb,
        const unsigned short* __restrict__ w2b, const float* __restrict__ b2,
        const float* __restrict__ out, const int* __restrict__ src,
        const int* __restrict__ dst, float* __restrict__ agg){
  __shared__ float os[64*65];   // out[src[e]][i]; later msg[e][o]
  __shared__ int sidx[128];
  int mt = blockIdx.x;
  int tid = threadIdx.x;
  int wave = tid>>6, l = tid&63, lm = l&15, g = l>>4;
  if (tid < 64){
    int e = mt*64 + tid;
    sidx[tid]    = (e < N_EDGES) ? src[e] : -1;
    sidx[64+tid] = (e < N_EDGES) ? dst[e] : -1;
  }
  __syncthreads();
  { // stage os[edge][i]
    int el = tid>>2, i0 = (tid&3)*16;
    int sn = sidx[el];
    #pragma unroll
    for (int j = 0; j < 16; j += 4){
      float4 v;
      if (sn >= 0) v = *(const float4*)(out + (size_t)sn*64 + i0 + j);
      else { v.x = v.y = v.z = v.w = 0.f; }
      os[el*65+i0+j]   = v.x; os[el*65+i0+j+1] = v.y;
      os[el*65+i0+j+2] = v.z; os[el*65+i0+j+3] = v.w;
    }
  }
  // afr: all 64 edges of the block (each wave loads all; o-slices differ)
  short8 afr[4][4];
  #pragma unroll
  for (int ms = 0; ms < 4; ++ms){
    int e = mt*64 + ms*16 + lm;
    bool ok = (e < N_EDGES);
    #pragma unroll
    for (int kk = 0; kk < 4; ++kk)
      afr[ms][kk] = ok ? *(const short8*)(hidb + (size_t)e*128 + kk*32 + 8*g) : zero8();
  }
  __syncthreads();
  f32x4 msgacc[4];
  #pragma unroll
  for (int ms=0;ms<4;++ms){ f32x4 z = {0.f,0.f,0.f,0.f}; msgacc[ms] = z; }
  const unsigned short* wrow = w2b + (size_t)(wave*16 + lm)*128 + 8*g;
  for (int i = 0; i < 64; ++i){
    short8 bfr[4];
    #pragma unroll
    for (int kk = 0; kk < 4; ++kk)
      bfr[kk] = *(const short8*)(wrow + (size_t)i*8192 + kk*32);
    f32x4 acc[4];
    #pragma unroll
    for (int ms=0;ms<4;++ms){ f32x4 z = {0.f,0.f,0.f,0.f}; acc[ms] = z; }
    #pragma unroll
    for (int kk = 0; kk < 4; ++kk){
      #pragma unroll
      for (int ms = 0; ms < 4; ++ms)
        acc[ms] = __builtin_amdgcn_mfma_f32_16x16x32_bf16(bfr[kk], afr[ms][kk], acc[ms], 0,0,0);
    }
    float4 bv = *(const float4*)(b2 + i*64 + wave*16 + 4*g);
    #pragma unroll
    for (int ms = 0; ms < 4; ++ms){
      float ov = os[(ms*16+lm)*65 + i];
      msgacc[ms][0] += (acc[ms][0]+bv.x)*ov;
      msgacc[ms][1] += (acc[ms][1]+bv.y)*ov;
      msgacc[ms][2] += (acc[ms][2]+bv.z)*ov;
      msgacc[ms][3] += (acc[ms][3]+bv.w)*ov;
    }
  }
  __syncthreads();   // os reads done; reuse as msg[edge][o]
  #pragma unroll
  for (int ms = 0; ms < 4; ++ms){
    #pragma unroll
    for (int r = 0; r < 4; ++r)
      os[(ms*16+lm)*65 + wave*16 + 4*g + r] = msgacc[ms][r];
  }
  __syncthreads();
  { // scatter
    int el = tid>>2, o0 = (tid&3)*16;
    int dn = sidx[64+el];
    if (dn >= 0){
      float* ap = agg + (size_t)dn*64 + o0;
      #pragma unroll
      for (int j = 0; j < 16; ++j) atomicAdd(ap + j, os[el*65+o0+j]);
    }
  }
}

// ---- fused: m = relu(agg/deg + out@root^T + cb); GRU(m, h=out) -> out ----
// also zeroes agg for the next layer.
__global__ __launch_bounds__(256) void k_update(float* __restrict__ out, unsigned short* __restrict__ outb,
        float* __restrict__ agg, const float* __restrict__ deg,
        const unsigned short* __restrict__ rootb, const float* __restrict__ convb,
        const unsigned short* __restrict__ wihb, const unsigned short* __restrict__ whhb,
        const float* __restrict__ bih, const float* __restrict__ bhh){
  __shared__ unsigned short ms_[4][1024];
  int wave = threadIdx.x >> 6;
  int l = threadIdx.x & 63;
  int lm = l & 15, g = l >> 4;
  int m0 = blockIdx.x*64 + wave*16;
  short8 ah[2];
  {
    int r = m0 + lm; bool ok = r < N_NODES;
    #pragma unroll
    for (int kk = 0; kk < 2; ++kk)
      ah[kk] = ok ? *(const short8*)(outb + (size_t)r*64 + kk*32 + 8*g) : zero8();
  }
  float dinv[4];
  #pragma unroll
  for (int i = 0; i < 4; ++i){
    int r = m0 + 4*g + i;
    dinv[i] = 1.0f / fmaxf((r < N_NODES) ? deg[r] : 1.f, 1.0f);
  }
  #pragma unroll
  for (int nt = 0; nt < 4; ++nt){
    f32x4 acc = {0.f,0.f,0.f,0.f};
    #pragma unroll
    for (int kk = 0; kk < 2; ++kk){
      short8 b = *(const short8*)(rootb + (size_t)(nt*16+lm)*64 + kk*32 + 8*g);
      acc = __builtin_amdgcn_mfma_f32_16x16x32_bf16(ah[kk], b, acc, 0,0,0);
    }
    int c = nt*16 + lm;
    #pragma unroll
    for (int i = 0; i < 4; ++i){
      int lr = 4*g + i, r = m0 + lr;
      float v = 0.f;
      if (r < N_NODES){
        size_t ix = (size_t)r*64 + c;
        v = fmaxf(acc[i] + agg[ix]*dinv[i] + convb[c], 0.f);
        agg[ix] = 0.f;
      }
      ms_[wave][(lr*64 + c) ^ ((lr&7)<<3)] = f2bf(v);
    }
  }
  __syncthreads();
  short8 am[2];
  #pragma unroll
  for (int kk = 0; kk < 2; ++kk)
    am[kk] = *(const short8*)(&ms_[wave][(lm*64 + kk*32 + 8*g) ^ ((lm&7)<<3)]);
  f32x4 accg[12], acch[12];
  #pragma unroll
  for (int nt = 0; nt < 12; ++nt){ f32x4 z = {0.f,0.f,0.f,0.f}; accg[nt]=z; acch[nt]=z; }
  #pragma unroll
  for (int nt = 0; nt < 12; ++nt){
    #pragma unroll
    for (int kk = 0; kk < 2; ++kk){
      short8 bg = *(const short8*)(wihb + (size_t)(nt*16+lm)*64 + kk*32 + 8*g);
      accg[nt] = __builtin_amdgcn_mfma_f32_16x16x32_bf16(am[kk], bg, accg[nt], 0,0,0);
      short8 bh = *(const short8*)(whhb + (size_t)(nt*16+lm)*64 + kk*32 + 8*g);
      acch[nt] = __builtin_amdgcn_mfma_f32_16x16x32_bf16(ah[kk], bh, acch[nt], 0,0,0);
    }
  }
  #pragma unroll
  for (int nt = 0; nt < 4; ++nt){
    int c = nt*16 + lm;
    #pragma unroll
    for (int i = 0; i < 4; ++i){
      int r = m0 + 4*g + i;
      if (r < N_NODES){
        float ir = accg[nt][i]   + bih[c],     hr = acch[nt][i]   + bhh[c];
        float iz = accg[nt+4][i] + bih[64+c],  hz = acch[nt+4][i] + bhh[64+c];
        float in_= accg[nt+8][i] + bih[128+c], hn = acch[nt+8][i] + bhh[128+c];
        float rr = sigm(ir+hr), zz = sigm(iz+hz);
        float nn = tanhf(in_ + rr*hn);
        float hp = out[(size_t)r*64+c];
        float hv = (1.f-zz)*nn + zz*hp;
        out[(size_t)r*64+c] = hv;
        outb[(size_t)r*64+c] = f2bf(hv);
      }
    }
  }
}

// ====== Set2Set (3 steps) + lin1, one block (64 thr) per graph ======
__global__ __launch_bounds__(64) void k_s2s(const float* __restrict__ out,
        const int* __restrict__ batch,
        const float* __restrict__ wih, const float* __restrict__ whh,
        const float* __restrict__ bih, const float* __restrict__ bhh,
        const float* __restrict__ w1, const float* __restrict__ b1,
        float* __restrict__ outp){
  int b = blockIdx.x, o = threadIdx.x;
  int s, e2;
  { int lo = 0, hi = N_NODES;
    while (lo < hi){ int m = (lo+hi)>>1; if (batch[m] < b) lo = m+1; else hi = m; }
    s = lo; hi = N_NODES;
    while (lo < hi){ int m = (lo+hi)>>1; if (batch[m] < b+1) lo = m+1; else hi = m; }
    e2 = lo;
  }
  int cnt = e2 - s;
  __shared__ float sq[128];   // q_star
  __shared__ float sh[64];    // hl
  __shared__ float se[512];   // per-node e then a
  __shared__ float sinv[1];
  float hl = 0.f, cl = 0.f;
  sq[o] = 0.f; sq[64+o] = 0.f; sh[o] = 0.f;
  __syncthreads();
  for (int step = 0; step < 3; ++step){
    float gi = bih[o]      + bhh[o];
    float gf = bih[64+o]   + bhh[64+o];
    float gg = bih[128+o]  + bhh[128+o];
    float go = bih[192+o]  + bhh[192+o];
    #pragma unroll 4
    for (int k = 0; k < 128; k += 4){
      float4 q4 = *(const float4*)(sq+k);
      float4 a4 = *(const float4*)(wih + (size_t)o*128 + k);
      float4 b4 = *(const float4*)(wih + (size_t)(64+o)*128 + k);
      float4 c4 = *(const float4*)(wih + (size_t)(128+o)*128 + k);
      float4 d4 = *(const float4*)(wih + (size_t)(192+o)*128 + k);
      gi += q4.x*a4.x + q4.y*a4.y + q4.z*a4.z + q4.w*a4.w;
      gf += q4.x*b4.x + q4.y*b4.y + q4.z*b4.z + q4.w*b4.w;
      gg += q4.x*c4.x + q4.y*c4.y + q4.z*c4.z + q4.w*c4.w;
      go += q4.x*d4.x + q4.y*d4.y + q4.z*d4.z + q4.w*d4.w;
    }
    #pragma unroll 4
    for (int k = 0; k < 64; k += 4){
      float4 h4 = *(const float4*)(sh+k);
      float4 a4 = *(const float4*)(whh + (size_t)o*64 + k);
      float4 b4 = *(const float4*)(whh + (size_t)(64+o)*64 + k);
      float4 c4 = *(const float4*)(whh + (size_t)(128+o)*64 + k);
      float4 d4 = *(const float4*)(whh + (size_t)(192+o)*64 + k);
      gi += h4.x*a4.x + h4.y*a4.y + h4.z*a4.z + h4.w*a4.w;
      gf += h4.x*b4.x + h4.y*b4.y + h4.z*b4.z + h4.w*b4.w;
      gg += h4.x*c4.x + h4.y*c4.y + h4.z*c4.z + h4.w*c4.w;
      go += h4.x*d4.x + h4.y*d4.y + h4.z*d4.z + h4.w*d4.w;
    }
    cl = sigm(gf)*cl + sigm(gi)*tanhf(gg);
    hl = sigm(go)*tanhf(cl);
    __syncthreads();
    sh[o] = hl; sq[o] = hl;
    __syncthreads();
    for (int j = o; j < cnt; j += 64){
      const float* op = out + (size_t)(s+j)*64;
      float d = 0.f;
      #pragma unroll 4
      for (int k = 0; k < 64; k += 4){
        float4 v  = *(const float4*)(op+k);
        float4 q4 = *(const float4*)(sq+k);
        d += v.x*q4.x + v.y*q4.y + v.z*q4.z + v.w*q4.w;
      }
      if (j < 512) se[j] = d;
    }
    __syncthreads();
    if (o == 0){
      float mx = -INFINITY;
      int c2 = cnt < 512 ? cnt : 512;
      for (int j = 0; j < c2; ++j) mx = fmaxf(mx, se[j]);
      float sm = 0.f;
      for (int j = 0; j < c2; ++j){ float a = __expf(se[j]-mx); se[j] = a; sm += a; }
      sinv[0] = (c2 > 0) ? 1.0f/sm : 0.f;
    }
    __syncthreads();
    float rv = 0.f;
    { int c2 = cnt < 512 ? cnt : 512;
      for (int j = 0; j < c2; ++j) rv += se[j]*out[(size_t)(s+j)*64 + o]; }
    rv *= sinv[0];
    __syncthreads();
    sq[64+o] = rv;
    __syncthreads();
  }
  float sacc = b1[o];
  #pragma unroll 4
  for (int k = 0; k < 128; k += 4){
    float4 q4 = *(const float4*)(sq+k);
    float4 w4 = *(const float4*)(w1 + (size_t)o*128 + k);
    sacc += q4.x*w4.x + q4.y*w4.y + q4.z*w4.z + q4.w*w4.w;
  }
  outp[(size_t)b*64 + o] = fmaxf(sacc, 0.f);
}

extern "C" void kernel_launch(void* const* d_in, const int* in_sizes, int n_in,
                              void* d_out, int out_size, void* d_ws, size_t ws_size,
                              hipStream_t stream){
  (void)in_sizes; (void)n_in; (void)out_size; (void)ws_size;
  const float* x      = (const float*)d_in[0];
  const float* eattr  = (const float*)d_in[1];
  const float* lin0w  = (const float*)d_in[2];
  const float* lin0b  = (const float*)d_in[3];
  const float* mlp1w  = (const float*)d_in[4];
  const float* mlp1b  = (const float*)d_in[5];
  const float* mlp2w  = (const float*)d_in[6];
  const float* mlp2b_ = (const float*)d_in[7];
  const float* rootw  = (const float*)d_in[8];
  const float* convb  = (const float*)d_in[9];
  const float* gwih   = (const float*)d_in[10];
  const float* gwhh   = (const float*)d_in[11];
  const float* gbih   = (const float*)d_in[12];
  const float* gbhh   = (const float*)d_in[13];
  const float* lwih   = (const float*)d_in[14];
  const float* lwhh   = (const float*)d_in[15];
  const float* lbih   = (const float*)d_in[16];
  const float* lbhh   = (const float*)d_in[17];
  const float* lin1w  = (const float*)d_in[18];
  const float* lin1b  = (const float*)d_in[19];
  const int*   eidx   = (const int*)d_in[20];
  const int*   batch  = (const int*)d_in[21];
  const int* srcp = eidx;
  const int* dstp = eidx + N_EDGES;

  char* ws = (char*)d_ws;
  size_t off = 0;
  auto take = [&](size_t bytes)->char*{
    char* p = ws + off; off = (off + bytes + 255) & ~(size_t)255; return p;
  };
  float* out           = (float*)take((size_t)N_NODES*64*4);
  unsigned short* outb = (unsigned short*)take((size_t)N_NODES*64*2);
  unsigned short* hidb = (unsigned short*)take((size_t)N_EDGES*128*2);
  float* agg           = (float*)take((size_t)N_NODES*64*4);
  float* deg           = (float*)take((size_t)N_NODES*4);
  unsigned short* w2b   = (unsigned short*)take((size_t)524288*2);
  unsigned short* rootb = (unsigned short*)take(4096*2);
  unsigned short* wihb  = (unsigned short*)take(12288*2);
  unsigned short* whhb  = (unsigned short*)take(12288*2);

  hipMemsetAsync(deg, 0, (size_t)N_NODES*4, stream);
  hipMemsetAsync(agg, 0, (size_t)N_NODES*64*4, stream);
  k_front<<<FB_CVT+FB_LIN0+FB_MLP1+FB_DEG,256,0,stream>>>(
      x, lin0w, lin0b, out, outb, eattr, mlp1w, mlp1b, hidb, dstp, deg,
      mlp2w, rootw, gwih, gwhh, w2b, rootb, wihb, whhb);
  for (int layer = 0; layer < 3; ++layer){
    k_msgf<<<(N_EDGES+63)/64,256,0,stream>>>(hidb, w2b, mlp2b_, out, srcp, dstp, agg);
    k_update<<<(N_NODES+63)/64,256,0,stream>>>(out, outb, agg, deg, rootb, convb,
                                               wihb, whhb, gbih, gbhh);
  }
  k_s2s<<<NGRAPH,64,0,stream>>>(out, batch, lwih, lwhh, lbih, lbhh, lin1w, lin1b,
                                (float*)d_out);
}